// Round 11
// baseline (329.638 us; speedup 1.0000x reference)
//
#include <hip/hip_runtime.h>
#include <hip/hip_bf16.h>

typedef __bf16 bf16x8 __attribute__((ext_vector_type(8)));
typedef __bf16 bf16x2 __attribute__((ext_vector_type(2)));
typedef float f32x4 __attribute__((ext_vector_type(4)));

#define NN 100000
#define DD 128
#define NE 600000
#define SLOTS 32
#define DEGSTRIDE 16   // one deg counter per 64B line (atomic false-sharing fix)

// ---------------- fused prep ----------------
// x->bf16, W->bf16, deg clear, slots prefill with SENTINEL=NN, zero row NN in Xb/Hb.
// grid covers NN*SLOTS = 3.2M threads (largest index space).
__global__ void prep(const float4* __restrict__ x4, __bf16* __restrict__ Xb,
                     __bf16* __restrict__ Hb,
                     const float* __restrict__ W1, const float* __restrict__ W2,
                     __bf16* __restrict__ W1b, __bf16* __restrict__ W2b,
                     int* __restrict__ degp, int* __restrict__ slots) {
    int i = blockIdx.x * blockDim.x + threadIdx.x;
    if (i < NN * DD / 4) {
        float4 v = x4[i];
        bf16x2 a, b;
        a[0] = (__bf16)v.x; a[1] = (__bf16)v.y;
        b[0] = (__bf16)v.z; b[1] = (__bf16)v.w;
        *reinterpret_cast<bf16x2*>(Xb + (size_t)i * 4)     = a;
        *reinterpret_cast<bf16x2*>(Xb + (size_t)i * 4 + 2) = b;
    }
    if (i < 3 * DD * DD) { W1b[i] = (__bf16)W1[i]; W2b[i] = (__bf16)W2[i]; }
    if (i < NN * DEGSTRIDE) degp[i] = 0;
    if (i < NN * SLOTS) slots[i] = NN;                      // sentinel -> zero row
    if (i < DD) { Xb[(size_t)NN * DD + i] = (__bf16)0.f;    // zero row NN
                  Hb[(size_t)NN * DD + i] = (__bf16)0.f; }
}

// ---------------- adjacency build (line-padded counters) ----------------
__global__ void fill_slots(const int* __restrict__ src, const int* __restrict__ dst,
                           int* __restrict__ degp, int* __restrict__ slots, int nE) {
    int e = blockIdx.x * blockDim.x + threadIdx.x;
    if (e >= nE) return;
    int d = dst[e];
    int pos = atomicAdd(&degp[(size_t)d * DEGSTRIDE], 1);
    if (pos < SLOTS) slots[(size_t)d * SLOTS + pos] = src[e];
}

// ---------------- aggregate: z[n] = h[n] + sum_{s in adj(n)} h[s] (bf16 in/out) ----------------
// 16-lane group per node, 8 dims/lane (bf16x8 = 16B). Sentinel design: unused slots
// hold NN -> gather the zero row -> accumulate UNCONDITIONALLY (no cndmask, no deg
// dependence in the accumulate). deg only gates the rare extra rounds. Width-16 shfl
// keeps broadcast sources inside the active group. Grid exact: 6250*16 == NN.
__global__ __launch_bounds__(256) void aggregate(const __bf16* __restrict__ h,
                                                 const int* __restrict__ degp,
                                                 const int* __restrict__ slots,
                                                 __bf16* __restrict__ z) {
    const int tid = threadIdx.x;
    const int grp = tid >> 4;            // 0..15 (node within block)
    const int lm  = tid & 15;
    const int n = blockIdx.x * 16 + grp;
    const int off = lm * 8;

    const int* sl = slots + (size_t)n * SLOTS;
    int myidx = sl[lm];                                   // sentinel-safe, unconditional
    const bf16x8 sv = *reinterpret_cast<const bf16x8*>(h + (size_t)n * DD + off);
    int d = degp[(size_t)n * DEGSTRIDE];                  // branch-gating only

    float acc[8];
#pragma unroll
    for (int i = 0; i < 8; ++i) acc[i] = (float)sv[i];

    // round 1: slots 0..7, fully unconditional
    {
        int s[8];
#pragma unroll
        for (int q = 0; q < 8; ++q) s[q] = __shfl(myidx, q, 16);
        bf16x8 v[8];
#pragma unroll
        for (int q = 0; q < 8; ++q) v[q] = *reinterpret_cast<const bf16x8*>(h + (size_t)s[q] * DD + off);
#pragma unroll
        for (int q = 0; q < 8; ++q)
#pragma unroll
            for (int i = 0; i < 8; ++i) acc[i] += (float)v[q][i];
    }
    // round 2: slots 8..15 (P(d>8) ~ 0.15)
    if (d > 8) {
        int s[8];
#pragma unroll
        for (int q = 0; q < 8; ++q) s[q] = __shfl(myidx, 8 + q, 16);
        bf16x8 v[8];
#pragma unroll
        for (int q = 0; q < 8; ++q) v[q] = *reinterpret_cast<const bf16x8*>(h + (size_t)s[q] * DD + off);
#pragma unroll
        for (int q = 0; q < 8; ++q)
#pragma unroll
            for (int i = 0; i < 8; ++i) acc[i] += (float)v[q][i];
    }
    // tier 2: slots 16..31 (extremely rare)
    if (d > 16) {
        int myidx2 = sl[16 + lm];
#pragma unroll
        for (int base = 0; base < 16; base += 8) {
            int s[8];
#pragma unroll
            for (int q = 0; q < 8; ++q) s[q] = __shfl(myidx2, base + q, 16);
            bf16x8 v[8];
#pragma unroll
            for (int q = 0; q < 8; ++q) v[q] = *reinterpret_cast<const bf16x8*>(h + (size_t)s[q] * DD + off);
#pragma unroll
            for (int q = 0; q < 8; ++q)
#pragma unroll
                for (int i = 0; i < 8; ++i) acc[i] += (float)v[q][i];
        }
    }

    bf16x8 o;
#pragma unroll
    for (int i = 0; i < 8; ++i) o[i] = (__bf16)acc[i];
    *reinterpret_cast<bf16x8*>(z + (size_t)n * DD + off) = o;
}

// ---------------- fused 2-layer MLP: H = relu(relu(Z@W1^T+b1)@W2^T+b2) ----------------
// B-fragments read DIRECTLY from global bf16 weights (L1/L2-hot 32KB; contiguous 16B
// per lane — pattern verified in round 7). No weight LDS, no restage barriers.
// tl rows are wave-private: GEMM1-epilogue write -> GEMM2 read needs no barrier
// (same-wave LDS ordering via lgkmcnt). LDS 34.8KB.
template<bool LAST>
__global__ __launch_bounds__(512, 4) void mlp_fused(const __bf16* __restrict__ A,
                                                    const __bf16* __restrict__ W1b,
                                                    const float* __restrict__ b1,
                                                    const __bf16* __restrict__ W2b,
                                                    const float* __restrict__ b2,
                                                    const float* __restrict__ Wf,
                                                    const float* __restrict__ bfp,
                                                    __bf16* __restrict__ Hout,
                                                    float* __restrict__ out, int N) {
    __shared__ __bf16 tl[128 * 136];
    const int tid = threadIdx.x;
    const int wave = tid >> 6;
    const int lane = tid & 63;
    const int lm = lane & 15;
    const int kg = lane >> 4;
    const int rowL = wave * 16;
    const int row0 = blockIdx.x * 128 + rowL;

    // ---- GEMM1: T = relu(Z @ W1^T + b1) ----
    f32x4 acc[8];
#pragma unroll
    for (int c = 0; c < 8; ++c) acc[c] = (f32x4){0.f, 0.f, 0.f, 0.f};

#pragma unroll
    for (int kk = 0; kk < 4; ++kk) {
        const int kbase = kk * 32 + kg * 8;
        int r = row0 + lm;
        if (r >= N) r = N - 1;
        const bf16x8 a = *reinterpret_cast<const bf16x8*>(A + (size_t)r * DD + kbase);
#pragma unroll
        for (int c = 0; c < 8; ++c) {
            const bf16x8 b = *reinterpret_cast<const bf16x8*>(W1b + (size_t)(c * 16 + lm) * DD + kbase);
            acc[c] = __builtin_amdgcn_mfma_f32_16x16x32_bf16(a, b, acc[c], 0, 0, 0);
        }
    }
    // epilogue -> tl (own wave's rows only; no barrier needed before GEMM2)
#pragma unroll
    for (int c = 0; c < 8; ++c) {
        const int col = c * 16 + lm;
        const float bv = b1[col];
#pragma unroll
        for (int j = 0; j < 4; ++j) {
            float v = acc[c][j] + bv;
            tl[(rowL + kg * 4 + j) * 136 + col] = (__bf16)(v > 0.f ? v : 0.f);
        }
    }

    // ---- GEMM2 ----
    f32x4 acc2[8];
#pragma unroll
    for (int c = 0; c < 8; ++c) acc2[c] = (f32x4){0.f, 0.f, 0.f, 0.f};

#pragma unroll
    for (int kk = 0; kk < 4; ++kk) {
        const int kbase = kk * 32 + kg * 8;
        const bf16x8 a2 = *reinterpret_cast<const bf16x8*>(&tl[(rowL + lm) * 136 + kbase]);
#pragma unroll
        for (int c = 0; c < 8; ++c) {
            const bf16x8 b = *reinterpret_cast<const bf16x8*>(W2b + (size_t)(c * 16 + lm) * DD + kbase);
            acc2[c] = __builtin_amdgcn_mfma_f32_16x16x32_bf16(a2, b, acc2[c], 0, 0, 0);
        }
    }

    if (!LAST) {
#pragma unroll
        for (int c = 0; c < 8; ++c) {
            const int col = c * 16 + lm;
            const float bv = b2[col];
#pragma unroll
            for (int j = 0; j < 4; ++j) {
                float v = acc2[c][j] + bv;
                tl[(rowL + kg * 4 + j) * 136 + col] = (__bf16)(v > 0.f ? v : 0.f);
            }
        }
        __syncthreads();   // cross-wave coalesced copy-out
        for (int i = tid; i < 128 * 16; i += 512) {
            int r = i >> 4, cc = (i & 15) * 8;
            int gr = blockIdx.x * 128 + r;
            if (gr < N) {
                bf16x8 v = *reinterpret_cast<const bf16x8*>(&tl[r * 136 + cc]);
                *reinterpret_cast<bf16x8*>(Hout + (size_t)gr * DD + cc) = v;
            }
        }
    } else {
        float wv[8];
#pragma unroll
        for (int c = 0; c < 8; ++c) wv[c] = Wf[c * 16 + lm];
        const float bias0 = bfp[0];
#pragma unroll
        for (int j = 0; j < 4; ++j) {
            float p = 0.f;
#pragma unroll
            for (int c = 0; c < 8; ++c) {
                const int col = c * 16 + lm;
                float v = acc2[c][j] + b2[col];
                p += (v > 0.f ? v : 0.f) * wv[c];
            }
            p += __shfl_xor(p, 1, 64);
            p += __shfl_xor(p, 2, 64);
            p += __shfl_xor(p, 4, 64);
            p += __shfl_xor(p, 8, 64);
            int row = row0 + kg * 4 + j;
            if (lm == 0 && row < N) out[row] = p + bias0;
        }
    }
}

extern "C" void kernel_launch(void* const* d_in, const int* in_sizes, int n_in,
                              void* d_out, int out_size, void* d_ws, size_t ws_size,
                              hipStream_t stream) {
    const float* x  = (const float*)d_in[0];
    const int*   ei = (const int*)d_in[1];
    const float* W1 = (const float*)d_in[2];
    const float* b1 = (const float*)d_in[3];
    const float* W2 = (const float*)d_in[4];
    const float* b2 = (const float*)d_in[5];
    const float* Wf = (const float*)d_in[6];
    const float* bf = (const float*)d_in[7];
    float* out = (float*)d_out;

    const int* src = ei;
    const int* dst = ei + NE;

    // Hb and Xb carry an extra zero row (index NN) for sentinel gathers
    __bf16* Zb   = (__bf16*)d_ws;                      // NN rows
    __bf16* Hb   = Zb + (size_t)NN * DD;               // NN+1 rows
    __bf16* Xb   = Hb + (size_t)(NN + 1) * DD;         // NN+1 rows
    __bf16* W1b  = Xb + (size_t)(NN + 1) * DD;         // 3*128*128
    __bf16* W2b  = W1b + 3 * DD * DD;
    int*  slots  = (int*)(W2b + 3 * DD * DD);          // NN*SLOTS
    int*  degp   = slots + (size_t)NN * SLOTS;         // NN*DEGSTRIDE

    const int aggGrid = NN / 16;                       // exact: 6250*16 == 100000
    const int mlpGrid = (NN + 127) / 128;
    const int prepGrid = (NN * SLOTS + 255) / 256;     // 3.2M threads

    prep<<<prepGrid, 256, 0, stream>>>((const float4*)x, Xb, Hb, W1, W2, W1b, W2b, degp, slots);
    fill_slots<<<(NE + 255) / 256, 256, 0, stream>>>(src, dst, degp, slots, NE);

    // block 0
    aggregate<<<aggGrid, 256, 0, stream>>>(Xb, degp, slots, Zb);
    mlp_fused<false><<<mlpGrid, 512, 0, stream>>>(Zb, W1b, b1, W2b, b2, Wf, bf, Hb, out, NN);
    // block 1
    aggregate<<<aggGrid, 256, 0, stream>>>(Hb, degp, slots, Zb);
    mlp_fused<false><<<mlpGrid, 512, 0, stream>>>(Zb, W1b + DD * DD, b1 + DD, W2b + DD * DD, b2 + DD,
                                                  Wf, bf, Hb, out, NN);
    // block 2 (+ fused final projection)
    aggregate<<<aggGrid, 256, 0, stream>>>(Hb, degp, slots, Zb);
    mlp_fused<true><<<mlpGrid, 512, 0, stream>>>(Zb, W1b + 2 * DD * DD, b1 + 2 * DD, W2b + 2 * DD * DD, b2 + 2 * DD,
                                                 Wf, bf, Hb, out, NN);
}

// Round 12
// 197.010 us; speedup vs baseline: 1.6732x; 1.6732x over previous
//
#include <hip/hip_runtime.h>
#include <hip/hip_bf16.h>

typedef __bf16 bf16x8 __attribute__((ext_vector_type(8)));
typedef __bf16 bf16x2 __attribute__((ext_vector_type(2)));
typedef float f32x4 __attribute__((ext_vector_type(4)));

#define NN 100000
#define DD 128
#define NE 600000
#define SLOTS 32
#define DEGSTRIDE 16   // one deg counter per 64B line (atomic false-sharing fix)

// ---------------- fused prep: x->bf16, W->bf16 (all 3 blocks), clear deg ----------------
__global__ void prep(const float4* __restrict__ x4, __bf16* __restrict__ Xb,
                     const float* __restrict__ W1, const float* __restrict__ W2,
                     __bf16* __restrict__ W1b, __bf16* __restrict__ W2b,
                     int* __restrict__ degp) {
    int i = blockIdx.x * blockDim.x + threadIdx.x;
    if (i < NN * DD / 4) {
        float4 v = x4[i];
        bf16x2 a, b;
        a[0] = (__bf16)v.x; a[1] = (__bf16)v.y;
        b[0] = (__bf16)v.z; b[1] = (__bf16)v.w;
        *reinterpret_cast<bf16x2*>(Xb + (size_t)i * 4)     = a;
        *reinterpret_cast<bf16x2*>(Xb + (size_t)i * 4 + 2) = b;
    }
    if (i < 3 * DD * DD) { W1b[i] = (__bf16)W1[i]; W2b[i] = (__bf16)W2[i]; }
    if (i < NN * DEGSTRIDE) degp[i] = 0;
}

// ---------------- adjacency build (line-padded counters) ----------------
__global__ void fill_slots(const int* __restrict__ src, const int* __restrict__ dst,
                           int* __restrict__ degp, int* __restrict__ slots, int nE) {
    int e = blockIdx.x * blockDim.x + threadIdx.x;
    if (e >= nE) return;
    int d = dst[e];
    int pos = atomicAdd(&degp[(size_t)d * DEGSTRIDE], 1);
    if (pos < SLOTS) slots[(size_t)d * SLOTS + pos] = src[e];
}

// ---------------- aggregate: z[n] = h[n] + sum_{s in adj(n)} h[s] (bf16 in/out) ----------------
// 16-lane group per node, 8 dims/lane (bf16x8 = 16B). Masked rounds of 8 gathers:
// all of a round's loads issue before any accumulate -> 8 outstanding gathers/round.
// d1 is group-uniform -> uniform trip counts; width-16 shfl keeps broadcast sources
// inside the active group (divergence-safe).
__global__ __launch_bounds__(256) void aggregate(const __bf16* __restrict__ h,
                                                 const int* __restrict__ degp,
                                                 const int* __restrict__ slots,
                                                 __bf16* __restrict__ z, int N) {
    const int tid = threadIdx.x;
    const int grp = tid >> 4;            // 0..15 (node within block)
    const int lm  = tid & 15;
    const int n = blockIdx.x * 16 + grp;
    if (n >= N) return;
    const int off = lm * 8;

    const bf16x8 sv = *reinterpret_cast<const bf16x8*>(h + (size_t)n * DD + off);
    float acc[8];
#pragma unroll
    for (int i = 0; i < 8; ++i) acc[i] = (float)sv[i];

    int d = degp[(size_t)n * DEGSTRIDE]; if (d > SLOTS) d = SLOTS;
    const int* sl = slots + (size_t)n * SLOTS;
    const int d1 = d < 16 ? d : 16;
    int myidx = (lm < d1) ? sl[lm] : 0;

    for (int base = 0; base < d1; base += 8) {
        int s[8];
#pragma unroll
        for (int q = 0; q < 8; ++q) s[q] = __shfl(myidx, base + q, 16);
        bf16x8 v[8];
#pragma unroll
        for (int q = 0; q < 8; ++q) v[q] = *reinterpret_cast<const bf16x8*>(h + (size_t)s[q] * DD + off);
#pragma unroll
        for (int q = 0; q < 8; ++q) {
            const bool ok = (base + q) < d1;
#pragma unroll
            for (int i = 0; i < 8; ++i) acc[i] += ok ? (float)v[q][i] : 0.f;
        }
    }

    if (d > 16) {
        const int d2 = d - 16;                 // <= 16
        int myidx2 = (lm < d2) ? sl[16 + lm] : 0;
        for (int base = 0; base < d2; base += 8) {
            int s[8];
#pragma unroll
            for (int q = 0; q < 8; ++q) s[q] = __shfl(myidx2, base + q, 16);
            bf16x8 v[8];
#pragma unroll
            for (int q = 0; q < 8; ++q) v[q] = *reinterpret_cast<const bf16x8*>(h + (size_t)s[q] * DD + off);
#pragma unroll
            for (int q = 0; q < 8; ++q) {
                const bool ok = (base + q) < d2;
#pragma unroll
                for (int i = 0; i < 8; ++i) acc[i] += ok ? (float)v[q][i] : 0.f;
            }
        }
    }

    bf16x8 o;
#pragma unroll
    for (int i = 0; i < 8; ++i) o[i] = (__bf16)acc[i];
    *reinterpret_cast<bf16x8*>(z + (size_t)n * DD + off) = o;
}

// ---------------- fused 2-layer MLP: H = relu(relu(Z@W1^T+b1)@W2^T+b2) ----------------
// bf16 pre-converted weights; ONE shared weight LDS buffer staged twice (W1 then W2):
// LDS 69.6KB -> 2 blocks/CU. Staging is essential: B-fragment reads are a 16B-granule
// scatter (256B lane stride) that must be served from LDS, not L2 (round-11 lesson).
// tl rows are wave-private, so barriers only guard wl restaging and the copy-out.
template<bool LAST>
__global__ __launch_bounds__(512, 4) void mlp_fused(const __bf16* __restrict__ A,
                                                    const __bf16* __restrict__ W1b,
                                                    const float* __restrict__ b1,
                                                    const __bf16* __restrict__ W2b,
                                                    const float* __restrict__ b2,
                                                    const float* __restrict__ Wf,
                                                    const float* __restrict__ bfp,
                                                    __bf16* __restrict__ Hout,
                                                    float* __restrict__ out, int N) {
    __shared__ __bf16 wl[128 * 136];
    __shared__ __bf16 tl[128 * 136];
    const int tid = threadIdx.x;

    for (int i = tid; i < 2048; i += 512) {
        int r = i >> 4, c = (i & 15) * 8;
        *reinterpret_cast<bf16x8*>(&wl[r * 136 + c]) =
            *reinterpret_cast<const bf16x8*>(W1b + (size_t)r * DD + c);
    }
    __syncthreads();

    const int wave = tid >> 6;
    const int lane = tid & 63;
    const int lm = lane & 15;
    const int kg = lane >> 4;
    const int rowL = wave * 16;
    const int row0 = blockIdx.x * 128 + rowL;

    // ---- GEMM1: T = relu(Z @ W1^T + b1) ----
    f32x4 acc[8];
#pragma unroll
    for (int c = 0; c < 8; ++c) acc[c] = (f32x4){0.f, 0.f, 0.f, 0.f};

#pragma unroll
    for (int kk = 0; kk < 4; ++kk) {
        const int kbase = kk * 32 + kg * 8;
        int r = row0 + lm;
        if (r >= N) r = N - 1;
        const bf16x8 a = *reinterpret_cast<const bf16x8*>(A + (size_t)r * DD + kbase);
#pragma unroll
        for (int c = 0; c < 8; ++c) {
            const bf16x8 b = *reinterpret_cast<const bf16x8*>(&wl[(c * 16 + lm) * 136 + kbase]);
            acc[c] = __builtin_amdgcn_mfma_f32_16x16x32_bf16(a, b, acc[c], 0, 0, 0);
        }
    }
#pragma unroll
    for (int c = 0; c < 8; ++c) {
        const int col = c * 16 + lm;
        const float bv = b1[col];
#pragma unroll
        for (int j = 0; j < 4; ++j) {
            float v = acc[c][j] + bv;
            tl[(rowL + kg * 4 + j) * 136 + col] = (__bf16)(v > 0.f ? v : 0.f);
        }
    }
    __syncthreads();   // all wl(W1) reads done before restage

    for (int i = tid; i < 2048; i += 512) {
        int r = i >> 4, c = (i & 15) * 8;
        *reinterpret_cast<bf16x8*>(&wl[r * 136 + c]) =
            *reinterpret_cast<const bf16x8*>(W2b + (size_t)r * DD + c);
    }
    __syncthreads();

    // ---- GEMM2 ----
    f32x4 acc2[8];
#pragma unroll
    for (int c = 0; c < 8; ++c) acc2[c] = (f32x4){0.f, 0.f, 0.f, 0.f};

#pragma unroll
    for (int kk = 0; kk < 4; ++kk) {
        const int kbase = kk * 32 + kg * 8;
        const bf16x8 a2 = *reinterpret_cast<const bf16x8*>(&tl[(rowL + lm) * 136 + kbase]);
#pragma unroll
        for (int c = 0; c < 8; ++c) {
            const bf16x8 b = *reinterpret_cast<const bf16x8*>(&wl[(c * 16 + lm) * 136 + kbase]);
            acc2[c] = __builtin_amdgcn_mfma_f32_16x16x32_bf16(a2, b, acc2[c], 0, 0, 0);
        }
    }

    if (!LAST) {
#pragma unroll
        for (int c = 0; c < 8; ++c) {
            const int col = c * 16 + lm;
            const float bv = b2[col];
#pragma unroll
            for (int j = 0; j < 4; ++j) {
                float v = acc2[c][j] + bv;
                tl[(rowL + kg * 4 + j) * 136 + col] = (__bf16)(v > 0.f ? v : 0.f);
            }
        }
        __syncthreads();
        for (int i = tid; i < 128 * 16; i += 512) {
            int r = i >> 4, cc = (i & 15) * 8;
            int gr = blockIdx.x * 128 + r;
            if (gr < N) {
                bf16x8 v = *reinterpret_cast<const bf16x8*>(&tl[r * 136 + cc]);
                *reinterpret_cast<bf16x8*>(Hout + (size_t)gr * DD + cc) = v;
            }
        }
    } else {
        float wv[8];
#pragma unroll
        for (int c = 0; c < 8; ++c) wv[c] = Wf[c * 16 + lm];
        const float bias0 = bfp[0];
#pragma unroll
        for (int j = 0; j < 4; ++j) {
            float p = 0.f;
#pragma unroll
            for (int c = 0; c < 8; ++c) {
                const int col = c * 16 + lm;
                float v = acc2[c][j] + b2[col];
                p += (v > 0.f ? v : 0.f) * wv[c];
            }
            p += __shfl_xor(p, 1, 64);
            p += __shfl_xor(p, 2, 64);
            p += __shfl_xor(p, 4, 64);
            p += __shfl_xor(p, 8, 64);
            int row = row0 + kg * 4 + j;
            if (lm == 0 && row < N) out[row] = p + bias0;
        }
    }
}

extern "C" void kernel_launch(void* const* d_in, const int* in_sizes, int n_in,
                              void* d_out, int out_size, void* d_ws, size_t ws_size,
                              hipStream_t stream) {
    const float* x  = (const float*)d_in[0];
    const int*   ei = (const int*)d_in[1];
    const float* W1 = (const float*)d_in[2];
    const float* b1 = (const float*)d_in[3];
    const float* W2 = (const float*)d_in[4];
    const float* b2 = (const float*)d_in[5];
    const float* Wf = (const float*)d_in[6];
    const float* bf = (const float*)d_in[7];
    float* out = (float*)d_out;

    const int* src = ei;
    const int* dst = ei + NE;

    __bf16* Zb   = (__bf16*)d_ws;                  // 25.6 MB
    __bf16* Hb   = Zb + (size_t)NN * DD;           // 25.6 MB
    __bf16* Xb   = Hb + (size_t)NN * DD;           // 25.6 MB
    __bf16* W1b  = Xb + (size_t)NN * DD;           // 96 KB
    __bf16* W2b  = W1b + 3 * DD * DD;              // 96 KB
    int*  slots  = (int*)(W2b + 3 * DD * DD);      // 12.8 MB
    int*  degp   = slots + (size_t)NN * SLOTS;     // 6.4 MB

    const int aggGrid = (NN + 15) / 16;
    const int mlpGrid = (NN + 127) / 128;
    const int prepGrid = (NN * DD / 4 + 255) / 256;

    prep<<<prepGrid, 256, 0, stream>>>((const float4*)x, Xb, W1, W2, W1b, W2b, degp);
    fill_slots<<<(NE + 255) / 256, 256, 0, stream>>>(src, dst, degp, slots, NE);

    // block 0
    aggregate<<<aggGrid, 256, 0, stream>>>(Xb, degp, slots, Zb, NN);
    mlp_fused<false><<<mlpGrid, 512, 0, stream>>>(Zb, W1b, b1, W2b, b2, Wf, bf, Hb, out, NN);
    // block 1
    aggregate<<<aggGrid, 256, 0, stream>>>(Hb, degp, slots, Zb, NN);
    mlp_fused<false><<<mlpGrid, 512, 0, stream>>>(Zb, W1b + DD * DD, b1 + DD, W2b + DD * DD, b2 + DD,
                                                  Wf, bf, Hb, out, NN);
    // block 2 (+ fused final projection)
    aggregate<<<aggGrid, 256, 0, stream>>>(Hb, degp, slots, Zb, NN);
    mlp_fused<true><<<mlpGrid, 512, 0, stream>>>(Zb, W1b + 2 * DD * DD, b1 + 2 * DD, W2b + 2 * DD * DD, b2 + 2 * DD,
                                                 Wf, bf, Hb, out, NN);
}